// Round 9
// baseline (584.446 us; speedup 1.0000x reference)
//
#include <hip/hip_runtime.h>
#include <hip/hip_bf16.h>

#define D      64
#define HID    36
#define IN_DIM 192
#define NPB    64        // nodes per bucket (node >> 6)
#define MAXNB  2048      // max buckets (n_nodes <= 131072)
#define CHUNK  4096      // endpoint records per partition block
#define SLICE  64        // partition-block rows per colscan slice

// ---------------------------------------------------------------------------
__global__ void zero_ws_kernel(float4* __restrict__ p, long n4) {
    long i = (long)blockIdx.x * blockDim.x + threadIdx.x;
    long stride = (long)gridDim.x * blockDim.x;
    float4 z = make_float4(0.f, 0.f, 0.f, 0.f);
    for (; i < n4; i += stride) p[i] = z;
}

// FALLBACK: R0 atomic scatter
__global__ __launch_bounds__(256) void scatter_kernel(
    const float* __restrict__ edges,
    const int* __restrict__ senders,
    const int* __restrict__ receivers,
    float* __restrict__ sent,
    float* __restrict__ recv,
    long total)
{
    long i = (long)blockIdx.x * blockDim.x + threadIdx.x;
    if (i >= total) return;
    long e = i >> 6;
    int  d = (int)(i & 63);
    float v = edges[i];
    unsafeAtomicAdd(&sent[(long)senders[e] * D + d], v);
    unsafeAtomicAdd(&recv[(long)receivers[e] * D + d], v);
}

// ---------------------------------------------------------------------------
// K_a: per-block bucket histogram.
// ---------------------------------------------------------------------------
__global__ __launch_bounds__(256) void count_kernel(
    const int* __restrict__ senders,
    const int* __restrict__ receivers,
    int* __restrict__ counts,          // [nblocks][NB]
    int NB, long E, long total_items)
{
    __shared__ int hist[MAXNB];
    for (int b = threadIdx.x; b < NB; b += 256) hist[b] = 0;
    __syncthreads();

    long start = (long)blockIdx.x * CHUNK;
    long end = start + CHUNK; if (end > total_items) end = total_items;
    for (long i = start + threadIdx.x; i < end; i += 256) {
        int node = (i < E) ? senders[i] : receivers[i - E];
        atomicAdd(&hist[node >> 6], 1);
    }
    __syncthreads();
    int* row = counts + (long)blockIdx.x * NB;
    for (int b = threadIdx.x; b < NB; b += 256) row[b] = hist[b];
}

// K_b1: within-slice column scan.  grid = (ceil(NB/256), S)
__global__ __launch_bounds__(256) void colscan1_kernel(
    int* __restrict__ counts, int* __restrict__ psum, int NB, int nblocks)
{
    int b = blockIdx.x * 256 + threadIdx.x;
    if (b >= NB) return;
    int s = blockIdx.y;
    int r0 = s * SLICE;
    int r1 = r0 + SLICE; if (r1 > nblocks) r1 = nblocks;
    int run = 0;
    for (int blk = r0; blk < r1; ++blk) {
        long idx = (long)blk * NB + b;
        int c = counts[idx];
        counts[idx] = run;
        run += c;
    }
    psum[(long)s * NB + b] = run;
}

// K_b2: merged colscan2 + basescan (single block, 1024 threads).
// Per column: scan slice sums -> tot; then block-wide exclusive scan of
// tot[NB] -> base[NB].
__global__ __launch_bounds__(1024) void colfinish_kernel(
    int* __restrict__ psum, int* __restrict__ tot, int* __restrict__ base,
    int NB, int S)
{
    __shared__ int sA[2][MAXNB];
    int t = threadIdx.x;

#pragma unroll
    for (int half = 0; half < 2; ++half) {
        int b = t + half * 1024;
        int run = 0;
        if (b < NB) {
            for (int s = 0; s < S; ++s) {
                long i = (long)s * NB + b;
                int v = psum[i];
                psum[i] = run;
                run += v;
            }
            tot[b] = run;
        }
        sA[0][b] = (b < NB) ? run : 0;
    }
    __syncthreads();

    int src = 0;
    for (int off = 1; off < MAXNB; off <<= 1) {
        int dst = src ^ 1;
        int i0 = t, i1 = t + 1024;
        sA[dst][i0] = sA[src][i0] + ((i0 >= off) ? sA[src][i0 - off] : 0);
        sA[dst][i1] = sA[src][i1] + ((i1 >= off) ? sA[src][i1 - off] : 0);
        src = dst;
        __syncthreads();
    }
    if (t < NB)        base[t]        = (t == 0) ? 0 : sA[src][t - 1];
    if (t + 1024 < NB) base[t + 1024] = sA[src][t + 1023];
}

// K_c: place records grouped by bucket. rec = edge<<7 | dir<<6 | node_lo
__global__ __launch_bounds__(256) void scatter_ids_kernel(
    const int* __restrict__ senders,
    const int* __restrict__ receivers,
    const int* __restrict__ counts,
    const int* __restrict__ psum,
    const int* __restrict__ base,
    unsigned* __restrict__ pool,
    int NB, long E, long total_items)
{
    __shared__ int cursor[MAXNB];
    const int* row = counts + (long)blockIdx.x * NB;
    const int* srow = psum + (long)(blockIdx.x / SLICE) * NB;
    for (int b = threadIdx.x; b < NB; b += 256)
        cursor[b] = row[b] + srow[b] + base[b];
    __syncthreads();

    long start = (long)blockIdx.x * CHUNK;
    long end = start + CHUNK; if (end > total_items) end = total_items;
    for (long i = start + threadIdx.x; i < end; i += 256) {
        int dir, node; long edge;
        if (i < E) { dir = 0; edge = i;     node = senders[i]; }
        else       { dir = 1; edge = i - E; node = receivers[i - E]; }
        int b = node >> 6;
        int pos = atomicAdd(&cursor[b], 1);
        pool[pos] = ((unsigned)edge << 7) | ((unsigned)dir << 6) | (unsigned)(node & 63);
    }
}

// ---------------------------------------------------------------------------
// K_e: per-bucket counting sort by key = (node_lo<<1)|dir (128 keys).
// Per-wave replicated hist/cursor (no cross-wave contention).
// ---------------------------------------------------------------------------
__global__ __launch_bounds__(256) void sort_bucket_kernel(
    const unsigned* __restrict__ pool,
    const int* __restrict__ base,
    const int* __restrict__ tot,
    unsigned* __restrict__ pool2,
    int4* __restrict__ seg,
    int n_nodes)
{
    __shared__ int hist[4][128];
    __shared__ int cursor[4][128];
    __shared__ int off[128], comb[128], tmp[128];

    int b = blockIdx.x, tid = threadIdx.x;
    int w = tid >> 6, lane = tid & 63;
    int bstart = base[b], cnt = tot[b];

    ((int*)hist)[tid] = 0;
    ((int*)hist)[tid + 256] = 0;
    __syncthreads();

    int q = (cnt + 3) >> 2;
    int rs = w * q;
    int re = rs + q; if (re > cnt) re = cnt;

    for (int i = rs + lane; i < re; i += 64) {
        unsigned r = pool[bstart + i];
        int key = ((r & 63) << 1) | ((r >> 6) & 1);
        atomicAdd(&hist[w][key], 1);
    }
    __syncthreads();

    if (tid < 128) {
        comb[tid] = hist[0][tid] + hist[1][tid] + hist[2][tid] + hist[3][tid];
        tmp[tid] = comb[tid];
    }
    __syncthreads();
    for (int d = 1; d < 128; d <<= 1) {
        int v = 0;
        if (tid < 128) v = (tid >= d) ? tmp[tid - d] : 0;
        __syncthreads();
        if (tid < 128) tmp[tid] += v;
        __syncthreads();
    }
    if (tid < 128) {
        int o = tmp[tid] - comb[tid];
        off[tid] = o;
        int c0 = o + hist[0][tid];
        int c1 = c0 + hist[1][tid];
        int c2 = c1 + hist[2][tid];
        cursor[0][tid] = o;
        cursor[1][tid] = c0;
        cursor[2][tid] = c1;
        cursor[3][tid] = c2;
    }
    __syncthreads();

    if (tid < 64) {
        int node = b * NPB + tid;
        if (node < n_nodes) {
            seg[node] = make_int4(bstart + off[tid * 2],     comb[tid * 2],
                                  bstart + off[tid * 2 + 1], comb[tid * 2 + 1]);
        }
    }

    for (int i = rs + lane; i < re; i += 64) {
        unsigned r = pool[bstart + i];
        int key = ((r & 63) << 1) | ((r >> 6) & 1);
        int pos = atomicAdd(&cursor[w][key], 1);
        pool2[bstart + pos] = r >> 7;          // bare edge id
    }
}

// ---------------------------------------------------------------------------
// K_f: FUSED gather + MLP. One wave per node, lane = feature.
// Direct broadcast id loads (no LDS staging), x16 unroll: up to 32 VMEM in
// flight per wave. MLP epilogue in-wave via sfeat LDS + shfl reduce.
// ---------------------------------------------------------------------------
__global__ __launch_bounds__(256) void gmlp_kernel(
    const float* __restrict__ edges,
    const unsigned* __restrict__ pool2,
    const int4* __restrict__ seg,
    const float* __restrict__ nodes,
    const float* __restrict__ W1,   // [192][36]
    const float* __restrict__ b1,   // [36]
    const float* __restrict__ W2,   // [36][2]
    const float* __restrict__ b2,   // [2]
    float* __restrict__ out,        // [n][2]
    int n_nodes)
{
    __shared__ float sfeat[4][IN_DIM];

    int w = threadIdx.x >> 6, lane = threadIdx.x & 63;
    int node = blockIdx.x * 4 + w;
    if (node >= n_nodes) return;

    int4 si = seg[node];
    float nf = nodes[(long)node * D + lane];   // issued early, overlaps gather

    float acc2[2];
#pragma unroll
    for (int dir = 0; dir < 2; ++dir) {
        int s = dir ? si.z : si.x;
        int c = dir ? si.w : si.y;
        float acc = 0.f;
        int j = 0;
        for (; j + 16 <= c; j += 16) {
            unsigned e0 = pool2[s+j],    e1 = pool2[s+j+1],  e2 = pool2[s+j+2],  e3 = pool2[s+j+3];
            unsigned e4 = pool2[s+j+4],  e5 = pool2[s+j+5],  e6 = pool2[s+j+6],  e7 = pool2[s+j+7];
            unsigned e8 = pool2[s+j+8],  e9 = pool2[s+j+9],  eA = pool2[s+j+10], eB = pool2[s+j+11];
            unsigned eC = pool2[s+j+12], eD = pool2[s+j+13], eE = pool2[s+j+14], eF = pool2[s+j+15];
            float v0 = edges[(long)e0 * D + lane];
            float v1 = edges[(long)e1 * D + lane];
            float v2 = edges[(long)e2 * D + lane];
            float v3 = edges[(long)e3 * D + lane];
            float v4 = edges[(long)e4 * D + lane];
            float v5 = edges[(long)e5 * D + lane];
            float v6 = edges[(long)e6 * D + lane];
            float v7 = edges[(long)e7 * D + lane];
            float v8 = edges[(long)e8 * D + lane];
            float v9 = edges[(long)e9 * D + lane];
            float vA = edges[(long)eA * D + lane];
            float vB = edges[(long)eB * D + lane];
            float vC = edges[(long)eC * D + lane];
            float vD = edges[(long)eD * D + lane];
            float vE = edges[(long)eE * D + lane];
            float vF = edges[(long)eF * D + lane];
            acc += (((v0 + v1) + (v2 + v3)) + ((v4 + v5) + (v6 + v7)))
                 + (((v8 + v9) + (vA + vB)) + ((vC + vD) + (vE + vF)));
        }
        for (; j + 4 <= c; j += 4) {
            unsigned e0 = pool2[s+j], e1 = pool2[s+j+1], e2 = pool2[s+j+2], e3 = pool2[s+j+3];
            float v0 = edges[(long)e0 * D + lane];
            float v1 = edges[(long)e1 * D + lane];
            float v2 = edges[(long)e2 * D + lane];
            float v3 = edges[(long)e3 * D + lane];
            acc += (v0 + v1) + (v2 + v3);
        }
        for (; j < c; ++j) acc += edges[(long)pool2[s+j] * D + lane];
        acc2[dir] = acc;
    }

    // stage feats = [nodes | sent | recv] for this node
    sfeat[w][lane]       = nf;
    sfeat[w][64 + lane]  = acc2[0];
    sfeat[w][128 + lane] = acc2[1];

    // MLP hidden: lanes 0..35 each compute one h[j]
    float h = 0.f;
    if (lane < HID) {
        float h0 = 0.f, h1 = 0.f, h2 = 0.f, h3 = 0.f;
        for (int k = 0; k < IN_DIM; k += 4) {
            h0 += sfeat[w][k]     * W1[(k)     * HID + lane];
            h1 += sfeat[w][k + 1] * W1[(k + 1) * HID + lane];
            h2 += sfeat[w][k + 2] * W1[(k + 2) * HID + lane];
            h3 += sfeat[w][k + 3] * W1[(k + 3) * HID + lane];
        }
        h = fmaxf(b1[lane] + ((h0 + h1) + (h2 + h3)), 0.f);
    }
    float p0 = (lane < HID) ? h * W2[lane * 2 + 0] : 0.f;
    float p1 = (lane < HID) ? h * W2[lane * 2 + 1] : 0.f;
#pragma unroll
    for (int off = 32; off; off >>= 1) {
        p0 += __shfl_down(p0, off, 64);
        p1 += __shfl_down(p1, off, 64);
    }
    if (lane == 0)
        reinterpret_cast<float2*>(out)[node] = make_float2(p0 + b2[0], p1 + b2[1]);
}

// ---------------------------------------------------------------------------
// per-node MLP (fallback path only)
// ---------------------------------------------------------------------------
__global__ __launch_bounds__(256) void mlp_kernel(
    const float* __restrict__ nodes,
    const float* __restrict__ sent,
    const float* __restrict__ recv,
    const float* __restrict__ W1,
    const float* __restrict__ b1,
    const float* __restrict__ W2,
    const float* __restrict__ b2,
    float* __restrict__ out,
    int n)
{
    __shared__ float sW1[IN_DIM * HID];
    __shared__ float sb1[HID];
    __shared__ float sW2[HID * 2];
    __shared__ float sb2[2];

    for (int t = threadIdx.x; t < IN_DIM * HID; t += blockDim.x) sW1[t] = W1[t];
    if (threadIdx.x < HID)     sb1[threadIdx.x] = b1[threadIdx.x];
    if (threadIdx.x < HID * 2) sW2[threadIdx.x] = W2[threadIdx.x];
    if (threadIdx.x < 2)       sb2[threadIdx.x] = b2[threadIdx.x];
    __syncthreads();

    int node = blockIdx.x * blockDim.x + threadIdx.x;
    if (node >= n) return;

    float acc[HID];
#pragma unroll
    for (int j = 0; j < HID; ++j) acc[j] = sb1[j];

#pragma unroll
    for (int part = 0; part < 3; ++part) {
        const float* f = (part == 0 ? nodes : (part == 1 ? sent : recv)) + (long)node * D;
        const float* wgt = sW1 + part * D * HID;
        for (int k = 0; k < D; k += 4) {
            float4 fv = *reinterpret_cast<const float4*>(f + k);
#pragma unroll
            for (int j = 0; j < HID; ++j) {
                acc[j] += fv.x * wgt[(k + 0) * HID + j];
                acc[j] += fv.y * wgt[(k + 1) * HID + j];
                acc[j] += fv.z * wgt[(k + 2) * HID + j];
                acc[j] += fv.w * wgt[(k + 3) * HID + j];
            }
        }
    }

    float o0 = sb2[0], o1 = sb2[1];
#pragma unroll
    for (int j = 0; j < HID; ++j) {
        float h = fmaxf(acc[j], 0.f);
        o0 += h * sW2[j * 2 + 0];
        o1 += h * sW2[j * 2 + 1];
    }
    reinterpret_cast<float2*>(out)[node] = make_float2(o0, o1);
}

// ---------------------------------------------------------------------------
extern "C" void kernel_launch(void* const* d_in, const int* in_sizes, int n_in,
                              void* d_out, int out_size, void* d_ws, size_t ws_size,
                              hipStream_t stream) {
    const float* nodes     = (const float*)d_in[0];
    const float* edges     = (const float*)d_in[1];
    const int*   senders   = (const int*)d_in[2];
    const int*   receivers = (const int*)d_in[3];
    const float* W1        = (const float*)d_in[4];
    const float* b1        = (const float*)d_in[5];
    const float* W2        = (const float*)d_in[6];
    const float* b2        = (const float*)d_in[7];
    float* out = (float*)d_out;

    const int  n_nodes = in_sizes[0] / D;      // 100,000
    const long E       = in_sizes[2];          // 3,200,000
    const long total_items = 2 * E;            // 6.4M endpoint records

    const int NB      = (n_nodes + NPB - 1) / NPB;                 // 1563
    const int nblocks = (int)((total_items + CHUNK - 1) / CHUNK);  // 1563
    const int S       = (nblocks + SLICE - 1) / SLICE;             // 25

    const size_t sz_sent = (size_t)n_nodes * D * sizeof(float);    // 25.6 MB
    const size_t sz_pool = (size_t)total_items * sizeof(unsigned); // 25.6 MB
    const size_t sz_seg  = (size_t)n_nodes * sizeof(int4);         // 1.6 MB
    const size_t sz_nb   = (size_t)MAXNB * sizeof(int);
    const size_t sz_psum = (size_t)S * NB * sizeof(int);           // ~156 KB
    const size_t need    = 2 * sz_sent + 2 * sz_pool + sz_seg + 2 * sz_nb + sz_psum;
    const size_t sz_counts = (size_t)nblocks * NB * sizeof(int);   // 9.8 MB

    char* wp = (char*)d_ws;
    float*    sent  = (float*)wp;           wp += sz_sent;
    float*    recv  = (float*)wp;           wp += sz_sent;
    unsigned* pool  = (unsigned*)wp;        wp += sz_pool;
    unsigned* pool2 = (unsigned*)wp;        wp += sz_pool;
    int4*     seg   = (int4*)wp;            wp += sz_seg;
    int*      tot   = (int*)wp;             wp += sz_nb;
    int*      base  = (int*)wp;             wp += sz_nb;
    int*      psum  = (int*)wp;
    int*      counts = (int*)sent;          // aliased; dead after scatter_ids

    if (ws_size < need || NB > MAXNB || sz_counts > sz_sent) {
        long n4 = (long)n_nodes * D * 2 / 4;
        zero_ws_kernel<<<2048, 256, 0, stream>>>((float4*)d_ws, n4);
        long total = E * D;
        scatter_kernel<<<(int)((total + 255) / 256), 256, 0, stream>>>(
            edges, senders, receivers, sent, recv, total);
        mlp_kernel<<<(n_nodes + 255) / 256, 256, 0, stream>>>(
            nodes, sent, recv, W1, b1, W2, b2, out, n_nodes);
        return;
    }

    count_kernel<<<nblocks, 256, 0, stream>>>(senders, receivers, counts,
                                              NB, E, total_items);
    {
        dim3 g1((NB + 255) / 256, S);
        colscan1_kernel<<<g1, 256, 0, stream>>>(counts, psum, NB, nblocks);
        colfinish_kernel<<<1, 1024, 0, stream>>>(psum, tot, base, NB, S);
    }
    scatter_ids_kernel<<<nblocks, 256, 0, stream>>>(senders, receivers, counts,
                                                    psum, base, pool, NB, E, total_items);
    sort_bucket_kernel<<<NB, 256, 0, stream>>>(pool, base, tot, pool2, seg, n_nodes);
    gmlp_kernel<<<(n_nodes + 3) / 4, 256, 0, stream>>>(edges, pool2, seg, nodes,
                                                       W1, b1, W2, b2, out, n_nodes);
}

// Round 10
// 539.706 us; speedup vs baseline: 1.0829x; 1.0829x over previous
//
#include <hip/hip_runtime.h>
#include <hip/hip_bf16.h>

#define D      64
#define HID    36
#define IN_DIM 192
#define NPB    256       // nodes per bucket (node >> 8)
#define NBMAX  512       // max buckets (n_nodes <= 131072)
#define KEYS   512       // NPB * 2 (node_lo, dir)
#define CHUNK  16384     // endpoint records per partition block
#define SLICE  64        // partition-block rows per colscan slice

// ---------------------------------------------------------------------------
__global__ void zero_ws_kernel(float4* __restrict__ p, long n4) {
    long i = (long)blockIdx.x * blockDim.x + threadIdx.x;
    long stride = (long)gridDim.x * blockDim.x;
    float4 z = make_float4(0.f, 0.f, 0.f, 0.f);
    for (; i < n4; i += stride) p[i] = z;
}

// FALLBACK: R0 atomic scatter
__global__ __launch_bounds__(256) void scatter_kernel(
    const float* __restrict__ edges,
    const int* __restrict__ senders,
    const int* __restrict__ receivers,
    float* __restrict__ sent,
    float* __restrict__ recv,
    long total)
{
    long i = (long)blockIdx.x * blockDim.x + threadIdx.x;
    if (i >= total) return;
    long e = i >> 6;
    int  d = (int)(i & 63);
    float v = edges[i];
    unsafeAtomicAdd(&sent[(long)senders[e] * D + d], v);
    unsafeAtomicAdd(&recv[(long)receivers[e] * D + d], v);
}

// ---------------------------------------------------------------------------
// K_a: per-block bucket histogram (bucket = node >> 8).
// record i in [0,2E): i<E -> (edge=i, dir=0, node=senders[i])
//                     else  (edge=i-E, dir=1, node=receivers[i-E])
// ---------------------------------------------------------------------------
__global__ __launch_bounds__(256) void count_kernel(
    const int* __restrict__ senders,
    const int* __restrict__ receivers,
    int* __restrict__ counts,          // [nblocks][NB]
    int NB, long E, long total_items)
{
    __shared__ int hist[NBMAX];
    for (int b = threadIdx.x; b < NB; b += 256) hist[b] = 0;
    __syncthreads();

    long start = (long)blockIdx.x * CHUNK;
    long end = start + CHUNK; if (end > total_items) end = total_items;
    for (long i = start + threadIdx.x; i < end; i += 256) {
        int node = (i < E) ? senders[i] : receivers[i - E];
        atomicAdd(&hist[node >> 8], 1);
    }
    __syncthreads();
    int* row = counts + (long)blockIdx.x * NB;
    for (int b = threadIdx.x; b < NB; b += 256) row[b] = hist[b];
}

// K_b1: within-slice column scan.  grid = (ceil(NB/256), S)
__global__ __launch_bounds__(256) void colscan1_kernel(
    int* __restrict__ counts, int* __restrict__ psum, int NB, int nblocks)
{
    int b = blockIdx.x * 256 + threadIdx.x;
    if (b >= NB) return;
    int s = blockIdx.y;
    int r0 = s * SLICE;
    int r1 = r0 + SLICE; if (r1 > nblocks) r1 = nblocks;
    int run = 0;
    for (int blk = r0; blk < r1; ++blk) {
        long idx = (long)blk * NB + b;
        int c = counts[idx];
        counts[idx] = run;
        run += c;
    }
    psum[(long)s * NB + b] = run;
}

// K_b2: merged colscan2 + basescan (single block, 512 threads).
__global__ __launch_bounds__(512) void colfinish_kernel(
    int* __restrict__ psum, int* __restrict__ tot, int* __restrict__ base,
    int NB, int S)
{
    __shared__ int sA[2][NBMAX];
    int t = threadIdx.x;            // 0..511

    int run = 0;
    if (t < NB) {
        for (int s = 0; s < S; ++s) {
            long i = (long)s * NB + t;
            int v = psum[i];
            psum[i] = run;
            run += v;
        }
        tot[t] = run;
    }
    sA[0][t] = (t < NB) ? run : 0;
    __syncthreads();

    int src = 0;
    for (int off = 1; off < NBMAX; off <<= 1) {
        int dst = src ^ 1;
        sA[dst][t] = sA[src][t] + ((t >= off) ? sA[src][t - off] : 0);
        src = dst;
        __syncthreads();
    }
    if (t < NB) base[t] = (t == 0) ? 0 : sA[src][t - 1];
}

// ---------------------------------------------------------------------------
// K_c v2: place records grouped by bucket with CLEAN burst writes.
// LDS counting sort of the block's CHUNK records by bucket, then each
// bucket's group is copied contiguously to its precomputed global cursor.
// rec = edge<<9 | dir<<8 | node_lo8   (requires E < 2^23)
// ---------------------------------------------------------------------------
__global__ __launch_bounds__(256) void scatter_ids_kernel(
    const int* __restrict__ senders,
    const int* __restrict__ receivers,
    const int* __restrict__ counts,
    const int* __restrict__ psum,
    const int* __restrict__ base,
    unsigned* __restrict__ pool,
    int NB, long E, long total_items)
{
    __shared__ unsigned recs[CHUNK];                    // 64 KB
    __shared__ int hist[NBMAX], off[NBMAX], cur[NBMAX], gb[NBMAX], tmp[NBMAX];

    int tid = threadIdx.x;
    for (int b = tid; b < NBMAX; b += 256) hist[b] = 0;
    __syncthreads();

    long start = (long)blockIdx.x * CHUNK;
    long end = start + (long)CHUNK; if (end > total_items) end = total_items;
    int cnt = (int)(end - start);

    // pass 1: histogram by bucket
    for (int i = tid; i < cnt; i += 256) {
        long gi = start + i;
        int node = (gi < E) ? senders[gi] : receivers[gi - E];
        atomicAdd(&hist[node >> 8], 1);
    }
    __syncthreads();

    // exclusive scan of hist (512 slots, 2 per thread)
    tmp[tid] = hist[tid];
    tmp[tid + 256] = hist[tid + 256];
    __syncthreads();
    for (int d = 1; d < NBMAX; d <<= 1) {
        int v0 = (tid >= d) ? tmp[tid - d] : 0;
        int v1 = (tid + 256 >= d) ? tmp[tid + 256 - d] : 0;
        __syncthreads();
        tmp[tid] += v0;
        tmp[tid + 256] += v1;
        __syncthreads();
    }
    {
        const int* row  = counts + (long)blockIdx.x * NB;
        const int* srow = psum + (long)(blockIdx.x / SLICE) * NB;
        for (int b = tid; b < NBMAX; b += 256) {
            int o = tmp[b] - hist[b];
            off[b] = o;
            cur[b] = o;
            if (b < NB) gb[b] = row[b] + srow[b] + base[b];
        }
    }
    __syncthreads();

    // pass 2: place records into LDS, sorted by bucket
    for (int i = tid; i < cnt; i += 256) {
        long gi = start + i;
        int dir, node; long edge;
        if (gi < E) { dir = 0; edge = gi;     node = senders[gi]; }
        else        { dir = 1; edge = gi - E; node = receivers[gi - E]; }
        int b = node >> 8;
        int pos = atomicAdd(&cur[b], 1);
        recs[pos] = ((unsigned)edge << 9) | ((unsigned)dir << 8) | (unsigned)(node & 255);
    }
    __syncthreads();

    // pass 3: burst-copy each bucket group (quarter-wave per bucket)
    int qw = tid >> 4, ql = tid & 15;
    for (int b = qw; b < NB; b += 16) {
        int o = off[b], c = hist[b];
        long g = gb[b];
        for (int k = ql; k < c; k += 16)
            pool[g + k] = recs[o + k];
    }
}

// ---------------------------------------------------------------------------
// K_e v2: per-bucket counting sort by key = (node_lo<<1)|dir (512 keys).
// Per-wave replicated hist/cursor. Emits pool2 (bare edge ids) + seg.
// ---------------------------------------------------------------------------
__global__ __launch_bounds__(256) void sort_bucket_kernel(
    const unsigned* __restrict__ pool,
    const int* __restrict__ base,
    const int* __restrict__ tot,
    unsigned* __restrict__ pool2,
    int4* __restrict__ seg,
    int n_nodes)
{
    __shared__ int hist[4][KEYS];     // 8 KB
    __shared__ int cursor[4][KEYS];   // 8 KB
    __shared__ int off[KEYS], comb[KEYS], tmp[KEYS];

    int b = blockIdx.x, tid = threadIdx.x;
    int w = tid >> 6, lane = tid & 63;
    int bstart = base[b], cnt = tot[b];

    for (int k = tid; k < 4 * KEYS; k += 256) ((int*)hist)[k] = 0;
    __syncthreads();

    int q = (cnt + 3) >> 2;
    int rs = w * q;
    int re = rs + q; if (re > cnt) re = cnt;

    for (int i = rs + lane; i < re; i += 64) {
        unsigned r = pool[bstart + i];
        int key = ((r & 255) << 1) | ((r >> 8) & 1);
        atomicAdd(&hist[w][key], 1);
    }
    __syncthreads();

    comb[tid]       = hist[0][tid] + hist[1][tid] + hist[2][tid] + hist[3][tid];
    comb[tid + 256] = hist[0][tid + 256] + hist[1][tid + 256]
                    + hist[2][tid + 256] + hist[3][tid + 256];
    tmp[tid] = comb[tid];
    tmp[tid + 256] = comb[tid + 256];
    __syncthreads();
    for (int d = 1; d < KEYS; d <<= 1) {
        int v0 = (tid >= d) ? tmp[tid - d] : 0;
        int v1 = (tid + 256 >= d) ? tmp[tid + 256 - d] : 0;
        __syncthreads();
        tmp[tid] += v0;
        tmp[tid + 256] += v1;
        __syncthreads();
    }
    for (int k = tid; k < KEYS; k += 256) {
        int o = tmp[k] - comb[k];
        off[k] = o;
        int c0 = o + hist[0][k];
        int c1 = c0 + hist[1][k];
        int c2 = c1 + hist[2][k];
        cursor[0][k] = o;  cursor[1][k] = c0;
        cursor[2][k] = c1; cursor[3][k] = c2;
    }
    __syncthreads();

    // seg for this bucket's 256 nodes
    {
        int node = b * NPB + tid;
        if (node < n_nodes)
            seg[node] = make_int4(bstart + off[tid * 2],     comb[tid * 2],
                                  bstart + off[tid * 2 + 1], comb[tid * 2 + 1]);
    }

    for (int i = rs + lane; i < re; i += 64) {
        unsigned r = pool[bstart + i];
        int key = ((r & 255) << 1) | ((r >> 8) & 1);
        int pos = atomicAdd(&cursor[w][key], 1);
        pool2[bstart + pos] = r >> 9;          // bare edge id
    }
}

// ---------------------------------------------------------------------------
// K_f: FUSED gather + MLP (R8-proven version: staged ids, x8 unroll).
// ---------------------------------------------------------------------------
__global__ __launch_bounds__(256) void gmlp_kernel(
    const float* __restrict__ edges,
    const unsigned* __restrict__ pool2,
    const int4* __restrict__ seg,
    const float* __restrict__ nodes,
    const float* __restrict__ W1,   // [192][36]
    const float* __restrict__ b1,   // [36]
    const float* __restrict__ W2,   // [36][2]
    const float* __restrict__ b2,   // [2]
    float* __restrict__ out,        // [n][2]
    int n_nodes)
{
    __shared__ unsigned sids[4][128];
    __shared__ float sfeat[4][IN_DIM];

    int w = threadIdx.x >> 6, lane = threadIdx.x & 63;
    int node = blockIdx.x * 4 + w;
    if (node >= n_nodes) return;

    int4 si = seg[node];

    float acc2[2];
#pragma unroll
    for (int dir = 0; dir < 2; ++dir) {
        int s = dir ? si.z : si.x;
        int c = dir ? si.w : si.y;
        float acc = 0.f;
        for (int b0 = 0; b0 < c; b0 += 128) {
            int m = c - b0; if (m > 128) m = 128;
            if (lane < m)      sids[w][lane]      = pool2[s + b0 + lane];
            if (64 + lane < m) sids[w][64 + lane] = pool2[s + b0 + 64 + lane];
            int t = 0;
            for (; t + 8 <= m; t += 8) {
                unsigned e0 = sids[w][t],     e1 = sids[w][t + 1];
                unsigned e2 = sids[w][t + 2], e3 = sids[w][t + 3];
                unsigned e4 = sids[w][t + 4], e5 = sids[w][t + 5];
                unsigned e6 = sids[w][t + 6], e7 = sids[w][t + 7];
                float v0 = edges[(long)e0 * D + lane];
                float v1 = edges[(long)e1 * D + lane];
                float v2 = edges[(long)e2 * D + lane];
                float v3 = edges[(long)e3 * D + lane];
                float v4 = edges[(long)e4 * D + lane];
                float v5 = edges[(long)e5 * D + lane];
                float v6 = edges[(long)e6 * D + lane];
                float v7 = edges[(long)e7 * D + lane];
                acc += ((v0 + v1) + (v2 + v3)) + ((v4 + v5) + (v6 + v7));
            }
            for (; t + 4 <= m; t += 4) {
                unsigned e0 = sids[w][t],     e1 = sids[w][t + 1];
                unsigned e2 = sids[w][t + 2], e3 = sids[w][t + 3];
                float v0 = edges[(long)e0 * D + lane];
                float v1 = edges[(long)e1 * D + lane];
                float v2 = edges[(long)e2 * D + lane];
                float v3 = edges[(long)e3 * D + lane];
                acc += (v0 + v1) + (v2 + v3);
            }
            for (; t < m; ++t) acc += edges[(long)sids[w][t] * D + lane];
        }
        acc2[dir] = acc;
    }

    float nf = nodes[(long)node * D + lane];
    sfeat[w][lane]       = nf;
    sfeat[w][64 + lane]  = acc2[0];
    sfeat[w][128 + lane] = acc2[1];

    float h = 0.f;
    if (lane < HID) {
        float h0 = 0.f, h1 = 0.f, h2 = 0.f, h3 = 0.f;
        for (int k = 0; k < IN_DIM; k += 4) {
            h0 += sfeat[w][k]     * W1[(k)     * HID + lane];
            h1 += sfeat[w][k + 1] * W1[(k + 1) * HID + lane];
            h2 += sfeat[w][k + 2] * W1[(k + 2) * HID + lane];
            h3 += sfeat[w][k + 3] * W1[(k + 3) * HID + lane];
        }
        h = fmaxf(b1[lane] + ((h0 + h1) + (h2 + h3)), 0.f);
    }
    float p0 = (lane < HID) ? h * W2[lane * 2 + 0] : 0.f;
    float p1 = (lane < HID) ? h * W2[lane * 2 + 1] : 0.f;
#pragma unroll
    for (int off = 32; off; off >>= 1) {
        p0 += __shfl_down(p0, off, 64);
        p1 += __shfl_down(p1, off, 64);
    }
    if (lane == 0)
        reinterpret_cast<float2*>(out)[node] = make_float2(p0 + b2[0], p1 + b2[1]);
}

// ---------------------------------------------------------------------------
// per-node MLP (fallback path only)
// ---------------------------------------------------------------------------
__global__ __launch_bounds__(256) void mlp_kernel(
    const float* __restrict__ nodes,
    const float* __restrict__ sent,
    const float* __restrict__ recv,
    const float* __restrict__ W1,
    const float* __restrict__ b1,
    const float* __restrict__ W2,
    const float* __restrict__ b2,
    float* __restrict__ out,
    int n)
{
    __shared__ float sW1[IN_DIM * HID];
    __shared__ float sb1[HID];
    __shared__ float sW2[HID * 2];
    __shared__ float sb2[2];

    for (int t = threadIdx.x; t < IN_DIM * HID; t += blockDim.x) sW1[t] = W1[t];
    if (threadIdx.x < HID)     sb1[threadIdx.x] = b1[threadIdx.x];
    if (threadIdx.x < HID * 2) sW2[threadIdx.x] = W2[threadIdx.x];
    if (threadIdx.x < 2)       sb2[threadIdx.x] = b2[threadIdx.x];
    __syncthreads();

    int node = blockIdx.x * blockDim.x + threadIdx.x;
    if (node >= n) return;

    float acc[HID];
#pragma unroll
    for (int j = 0; j < HID; ++j) acc[j] = sb1[j];

#pragma unroll
    for (int part = 0; part < 3; ++part) {
        const float* f = (part == 0 ? nodes : (part == 1 ? sent : recv)) + (long)node * D;
        const float* wgt = sW1 + part * D * HID;
        for (int k = 0; k < D; k += 4) {
            float4 fv = *reinterpret_cast<const float4*>(f + k);
#pragma unroll
            for (int j = 0; j < HID; ++j) {
                acc[j] += fv.x * wgt[(k + 0) * HID + j];
                acc[j] += fv.y * wgt[(k + 1) * HID + j];
                acc[j] += fv.z * wgt[(k + 2) * HID + j];
                acc[j] += fv.w * wgt[(k + 3) * HID + j];
            }
        }
    }

    float o0 = sb2[0], o1 = sb2[1];
#pragma unroll
    for (int j = 0; j < HID; ++j) {
        float h = fmaxf(acc[j], 0.f);
        o0 += h * sW2[j * 2 + 0];
        o1 += h * sW2[j * 2 + 1];
    }
    reinterpret_cast<float2*>(out)[node] = make_float2(o0, o1);
}

// ---------------------------------------------------------------------------
extern "C" void kernel_launch(void* const* d_in, const int* in_sizes, int n_in,
                              void* d_out, int out_size, void* d_ws, size_t ws_size,
                              hipStream_t stream) {
    const float* nodes     = (const float*)d_in[0];
    const float* edges     = (const float*)d_in[1];
    const int*   senders   = (const int*)d_in[2];
    const int*   receivers = (const int*)d_in[3];
    const float* W1        = (const float*)d_in[4];
    const float* b1        = (const float*)d_in[5];
    const float* W2        = (const float*)d_in[6];
    const float* b2        = (const float*)d_in[7];
    float* out = (float*)d_out;

    const int  n_nodes = in_sizes[0] / D;      // 100,000
    const long E       = in_sizes[2];          // 3,200,000
    const long total_items = 2 * E;            // 6.4M endpoint records

    const int NB      = (n_nodes + NPB - 1) / NPB;                 // 391
    const int nblocks = (int)((total_items + CHUNK - 1) / CHUNK);  // 391
    const int S       = (nblocks + SLICE - 1) / SLICE;             // 7

    const size_t sz_sent = (size_t)n_nodes * D * sizeof(float);    // 25.6 MB
    const size_t sz_pool = (size_t)total_items * sizeof(unsigned); // 25.6 MB
    const size_t sz_seg  = (size_t)n_nodes * sizeof(int4);         // 1.6 MB
    const size_t sz_nb   = (size_t)NBMAX * sizeof(int);
    const size_t sz_psum = (size_t)S * NB * sizeof(int);
    const size_t need    = 2 * sz_sent + 2 * sz_pool + sz_seg + 2 * sz_nb + sz_psum;
    const size_t sz_counts = (size_t)nblocks * NB * sizeof(int);   // 612 KB

    char* wp = (char*)d_ws;
    float*    sent  = (float*)wp;           wp += sz_sent;
    float*    recv  = (float*)wp;           wp += sz_sent;
    unsigned* pool  = (unsigned*)wp;        wp += sz_pool;
    unsigned* pool2 = (unsigned*)wp;        wp += sz_pool;
    int4*     seg   = (int4*)wp;            wp += sz_seg;
    int*      tot   = (int*)wp;             wp += sz_nb;
    int*      base  = (int*)wp;             wp += sz_nb;
    int*      psum  = (int*)wp;
    int*      counts = (int*)sent;          // aliased; dead after scatter_ids

    if (ws_size < need || NB > NBMAX || sz_counts > sz_sent || E >= (1L << 23)) {
        long n4 = (long)n_nodes * D * 2 / 4;
        zero_ws_kernel<<<2048, 256, 0, stream>>>((float4*)d_ws, n4);
        long total = E * D;
        scatter_kernel<<<(int)((total + 255) / 256), 256, 0, stream>>>(
            edges, senders, receivers, sent, recv, total);
        mlp_kernel<<<(n_nodes + 255) / 256, 256, 0, stream>>>(
            nodes, sent, recv, W1, b1, W2, b2, out, n_nodes);
        return;
    }

    count_kernel<<<nblocks, 256, 0, stream>>>(senders, receivers, counts,
                                              NB, E, total_items);
    {
        dim3 g1((NB + 255) / 256, S);
        colscan1_kernel<<<g1, 256, 0, stream>>>(counts, psum, NB, nblocks);
        colfinish_kernel<<<1, 512, 0, stream>>>(psum, tot, base, NB, S);
    }
    scatter_ids_kernel<<<nblocks, 256, 0, stream>>>(senders, receivers, counts,
                                                    psum, base, pool, NB, E, total_items);
    sort_bucket_kernel<<<NB, 256, 0, stream>>>(pool, base, tot, pool2, seg, n_nodes);
    gmlp_kernel<<<(n_nodes + 3) / 4, 256, 0, stream>>>(edges, pool2, seg, nodes,
                                                       W1, b1, W2, b2, out, n_nodes);
}

// Round 11
// 525.378 us; speedup vs baseline: 1.1124x; 1.0273x over previous
//
#include <hip/hip_runtime.h>
#include <hip/hip_bf16.h>

#define D      64
#define HID    36
#define IN_DIM 192
#define NPB    256       // nodes per bucket (node >> 8)
#define NBMAX  512       // max buckets (n_nodes <= 131072)
#define KEYS   512       // NPB * 2 (node_lo, dir)
#define CHUNK  8192      // endpoint records per partition block
#define SLICE  64        // partition-block rows per colscan slice

// ---------------------------------------------------------------------------
__global__ void zero_ws_kernel(float4* __restrict__ p, long n4) {
    long i = (long)blockIdx.x * blockDim.x + threadIdx.x;
    long stride = (long)gridDim.x * blockDim.x;
    float4 z = make_float4(0.f, 0.f, 0.f, 0.f);
    for (; i < n4; i += stride) p[i] = z;
}

// FALLBACK: R0 atomic scatter
__global__ __launch_bounds__(256) void scatter_kernel(
    const float* __restrict__ edges,
    const int* __restrict__ senders,
    const int* __restrict__ receivers,
    float* __restrict__ sent,
    float* __restrict__ recv,
    long total)
{
    long i = (long)blockIdx.x * blockDim.x + threadIdx.x;
    if (i >= total) return;
    long e = i >> 6;
    int  d = (int)(i & 63);
    float v = edges[i];
    unsafeAtomicAdd(&sent[(long)senders[e] * D + d], v);
    unsafeAtomicAdd(&recv[(long)receivers[e] * D + d], v);
}

// ---------------------------------------------------------------------------
// K_a: per-block bucket histogram (bucket = node >> 8), wave-replicated.
// record i in [0,2E): i<E -> (edge=i, dir=0, node=senders[i])
//                     else  (edge=i-E, dir=1, node=receivers[i-E])
// ---------------------------------------------------------------------------
__global__ __launch_bounds__(256) void count_kernel(
    const int* __restrict__ senders,
    const int* __restrict__ receivers,
    int* __restrict__ counts,          // [nblocks][NB]
    int NB, long E, long total_items)
{
    __shared__ int hist[4][NBMAX];     // 8 KB
    int tid = threadIdx.x, w = tid >> 6;
    for (int k = tid; k < 4 * NBMAX; k += 256) ((int*)hist)[k] = 0;
    __syncthreads();

    long start = (long)blockIdx.x * CHUNK;
    long end = start + CHUNK; if (end > total_items) end = total_items;
    for (long i = start + tid; i < end; i += 256) {
        int node = (i < E) ? senders[i] : receivers[i - E];
        atomicAdd(&hist[w][node >> 8], 1);
    }
    __syncthreads();
    int* row = counts + (long)blockIdx.x * NB;
    for (int b = tid; b < NB; b += 256)
        row[b] = hist[0][b] + hist[1][b] + hist[2][b] + hist[3][b];
}

// K_b1: within-slice column scan.  grid = (ceil(NB/256), S)
__global__ __launch_bounds__(256) void colscan1_kernel(
    int* __restrict__ counts, int* __restrict__ psum, int NB, int nblocks)
{
    int b = blockIdx.x * 256 + threadIdx.x;
    if (b >= NB) return;
    int s = blockIdx.y;
    int r0 = s * SLICE;
    int r1 = r0 + SLICE; if (r1 > nblocks) r1 = nblocks;
    int run = 0;
    for (int blk = r0; blk < r1; ++blk) {
        long idx = (long)blk * NB + b;
        int c = counts[idx];
        counts[idx] = run;
        run += c;
    }
    psum[(long)s * NB + b] = run;
}

// K_b2: merged colscan2 + basescan (single block, 512 threads).
__global__ __launch_bounds__(512) void colfinish_kernel(
    int* __restrict__ psum, int* __restrict__ tot, int* __restrict__ base,
    int NB, int S)
{
    __shared__ int sA[2][NBMAX];
    int t = threadIdx.x;            // 0..511

    int run = 0;
    if (t < NB) {
        for (int s = 0; s < S; ++s) {
            long i = (long)s * NB + t;
            int v = psum[i];
            psum[i] = run;
            run += v;
        }
        tot[t] = run;
    }
    sA[0][t] = (t < NB) ? run : 0;
    __syncthreads();

    int src = 0;
    for (int off = 1; off < NBMAX; off <<= 1) {
        int dst = src ^ 1;
        sA[dst][t] = sA[src][t] + ((t >= off) ? sA[src][t - off] : 0);
        src = dst;
        __syncthreads();
    }
    if (t < NB) base[t] = (t == 0) ? 0 : sA[src][t - 1];
}

// ---------------------------------------------------------------------------
// K_c v3: place records grouped by bucket, wave-replicated cursors.
// Each wave owns a contiguous quarter of the chunk; per-wave hist carves
// per-wave sub-segments of each bucket group (order within a group is
// irrelevant -- the gather sums segments). Burst-copy to global.
// rec = edge<<9 | dir<<8 | node_lo8   (requires E < 2^23)
// ---------------------------------------------------------------------------
__global__ __launch_bounds__(256) void scatter_ids_kernel(
    const int* __restrict__ senders,
    const int* __restrict__ receivers,
    const int* __restrict__ counts,
    const int* __restrict__ psum,
    const int* __restrict__ base,
    unsigned* __restrict__ pool,
    int NB, long E, long total_items)
{
    __shared__ unsigned recs[CHUNK];                       // 32 KB
    __shared__ int hist[4][NBMAX];                         // 8 KB
    __shared__ int cur[4][NBMAX];                          // 8 KB
    __shared__ int off[NBMAX], comb[NBMAX], tmp[NBMAX], gb[NBMAX];  // 8 KB

    int tid = threadIdx.x;
    int w = tid >> 6, lane = tid & 63;
    for (int k = tid; k < 4 * NBMAX; k += 256) ((int*)hist)[k] = 0;
    __syncthreads();

    long start = (long)blockIdx.x * CHUNK;
    long end = start + (long)CHUNK; if (end > total_items) end = total_items;
    int cnt = (int)(end - start);

    int q = (cnt + 3) >> 2;
    int rs = w * q;
    int re = rs + q; if (re > cnt) re = cnt;

    // pass 1: per-wave histogram over its quarter
    for (int i = rs + lane; i < re; i += 64) {
        long gi = start + i;
        int node = (gi < E) ? senders[gi] : receivers[gi - E];
        atomicAdd(&hist[w][node >> 8], 1);
    }
    __syncthreads();

    // combine + exclusive scan (512 slots, 2 per thread)
    comb[tid]       = hist[0][tid] + hist[1][tid] + hist[2][tid] + hist[3][tid];
    comb[tid + 256] = hist[0][tid + 256] + hist[1][tid + 256]
                    + hist[2][tid + 256] + hist[3][tid + 256];
    tmp[tid] = comb[tid];
    tmp[tid + 256] = comb[tid + 256];
    __syncthreads();
    for (int d = 1; d < NBMAX; d <<= 1) {
        int v0 = (tid >= d) ? tmp[tid - d] : 0;
        int v1 = (tid + 256 >= d) ? tmp[tid + 256 - d] : 0;
        __syncthreads();
        tmp[tid] += v0;
        tmp[tid + 256] += v1;
        __syncthreads();
    }
    {
        const int* row  = counts + (long)blockIdx.x * NB;
        const int* srow = psum + (long)(blockIdx.x / SLICE) * NB;
        for (int b = tid; b < NBMAX; b += 256) {
            int o = tmp[b] - comb[b];
            off[b] = o;
            int c0 = o + hist[0][b];
            int c1 = c0 + hist[1][b];
            int c2 = c1 + hist[2][b];
            cur[0][b] = o;  cur[1][b] = c0;
            cur[2][b] = c1; cur[3][b] = c2;
            if (b < NB) gb[b] = row[b] + srow[b] + base[b];
        }
    }
    __syncthreads();

    // pass 2: place records into LDS (per-wave cursors, ~5-way contention)
    for (int i = rs + lane; i < re; i += 64) {
        long gi = start + i;
        int dir, node; long edge;
        if (gi < E) { dir = 0; edge = gi;     node = senders[gi]; }
        else        { dir = 1; edge = gi - E; node = receivers[gi - E]; }
        int b = node >> 8;
        int pos = atomicAdd(&cur[w][b], 1);
        recs[pos] = ((unsigned)edge << 9) | ((unsigned)dir << 8) | (unsigned)(node & 255);
    }
    __syncthreads();

    // pass 3: burst-copy each bucket group (quarter-wave per bucket)
    int qw = tid >> 4, ql = tid & 15;
    for (int b = qw; b < NB; b += 16) {
        int o = off[b], c = comb[b];
        long g = gb[b];
        for (int k = ql; k < c; k += 16)
            pool[g + k] = recs[o + k];
    }
}

// ---------------------------------------------------------------------------
// K_e: per-bucket counting sort by key = (node_lo<<1)|dir (512 keys).
// Per-wave replicated hist/cursor. Emits pool2 (bare edge ids) + seg.
// ---------------------------------------------------------------------------
__global__ __launch_bounds__(256) void sort_bucket_kernel(
    const unsigned* __restrict__ pool,
    const int* __restrict__ base,
    const int* __restrict__ tot,
    unsigned* __restrict__ pool2,
    int4* __restrict__ seg,
    int n_nodes)
{
    __shared__ int hist[4][KEYS];     // 8 KB
    __shared__ int cursor[4][KEYS];   // 8 KB
    __shared__ int off[KEYS], comb[KEYS], tmp[KEYS];

    int b = blockIdx.x, tid = threadIdx.x;
    int w = tid >> 6, lane = tid & 63;
    int bstart = base[b], cnt = tot[b];

    for (int k = tid; k < 4 * KEYS; k += 256) ((int*)hist)[k] = 0;
    __syncthreads();

    int q = (cnt + 3) >> 2;
    int rs = w * q;
    int re = rs + q; if (re > cnt) re = cnt;

    for (int i = rs + lane; i < re; i += 64) {
        unsigned r = pool[bstart + i];
        int key = ((r & 255) << 1) | ((r >> 8) & 1);
        atomicAdd(&hist[w][key], 1);
    }
    __syncthreads();

    comb[tid]       = hist[0][tid] + hist[1][tid] + hist[2][tid] + hist[3][tid];
    comb[tid + 256] = hist[0][tid + 256] + hist[1][tid + 256]
                    + hist[2][tid + 256] + hist[3][tid + 256];
    tmp[tid] = comb[tid];
    tmp[tid + 256] = comb[tid + 256];
    __syncthreads();
    for (int d = 1; d < KEYS; d <<= 1) {
        int v0 = (tid >= d) ? tmp[tid - d] : 0;
        int v1 = (tid + 256 >= d) ? tmp[tid + 256 - d] : 0;
        __syncthreads();
        tmp[tid] += v0;
        tmp[tid + 256] += v1;
        __syncthreads();
    }
    for (int k = tid; k < KEYS; k += 256) {
        int o = tmp[k] - comb[k];
        off[k] = o;
        int c0 = o + hist[0][k];
        int c1 = c0 + hist[1][k];
        int c2 = c1 + hist[2][k];
        cursor[0][k] = o;  cursor[1][k] = c0;
        cursor[2][k] = c1; cursor[3][k] = c2;
    }
    __syncthreads();

    // seg for this bucket's 256 nodes
    {
        int node = b * NPB + tid;
        if (node < n_nodes)
            seg[node] = make_int4(bstart + off[tid * 2],     comb[tid * 2],
                                  bstart + off[tid * 2 + 1], comb[tid * 2 + 1]);
    }

    for (int i = rs + lane; i < re; i += 64) {
        unsigned r = pool[bstart + i];
        int key = ((r & 255) << 1) | ((r >> 8) & 1);
        int pos = atomicAdd(&cursor[w][key], 1);
        pool2[bstart + pos] = r >> 9;          // bare edge id
    }
}

// ---------------------------------------------------------------------------
// K_f: FUSED gather + MLP (R8-proven version: staged ids, x8 unroll).
// ---------------------------------------------------------------------------
__global__ __launch_bounds__(256) void gmlp_kernel(
    const float* __restrict__ edges,
    const unsigned* __restrict__ pool2,
    const int4* __restrict__ seg,
    const float* __restrict__ nodes,
    const float* __restrict__ W1,   // [192][36]
    const float* __restrict__ b1,   // [36]
    const float* __restrict__ W2,   // [36][2]
    const float* __restrict__ b2,   // [2]
    float* __restrict__ out,        // [n][2]
    int n_nodes)
{
    __shared__ unsigned sids[4][128];
    __shared__ float sfeat[4][IN_DIM];

    int w = threadIdx.x >> 6, lane = threadIdx.x & 63;
    int node = blockIdx.x * 4 + w;
    if (node >= n_nodes) return;

    int4 si = seg[node];

    float acc2[2];
#pragma unroll
    for (int dir = 0; dir < 2; ++dir) {
        int s = dir ? si.z : si.x;
        int c = dir ? si.w : si.y;
        float acc = 0.f;
        for (int b0 = 0; b0 < c; b0 += 128) {
            int m = c - b0; if (m > 128) m = 128;
            if (lane < m)      sids[w][lane]      = pool2[s + b0 + lane];
            if (64 + lane < m) sids[w][64 + lane] = pool2[s + b0 + 64 + lane];
            int t = 0;
            for (; t + 8 <= m; t += 8) {
                unsigned e0 = sids[w][t],     e1 = sids[w][t + 1];
                unsigned e2 = sids[w][t + 2], e3 = sids[w][t + 3];
                unsigned e4 = sids[w][t + 4], e5 = sids[w][t + 5];
                unsigned e6 = sids[w][t + 6], e7 = sids[w][t + 7];
                float v0 = edges[(long)e0 * D + lane];
                float v1 = edges[(long)e1 * D + lane];
                float v2 = edges[(long)e2 * D + lane];
                float v3 = edges[(long)e3 * D + lane];
                float v4 = edges[(long)e4 * D + lane];
                float v5 = edges[(long)e5 * D + lane];
                float v6 = edges[(long)e6 * D + lane];
                float v7 = edges[(long)e7 * D + lane];
                acc += ((v0 + v1) + (v2 + v3)) + ((v4 + v5) + (v6 + v7));
            }
            for (; t + 4 <= m; t += 4) {
                unsigned e0 = sids[w][t],     e1 = sids[w][t + 1];
                unsigned e2 = sids[w][t + 2], e3 = sids[w][t + 3];
                float v0 = edges[(long)e0 * D + lane];
                float v1 = edges[(long)e1 * D + lane];
                float v2 = edges[(long)e2 * D + lane];
                float v3 = edges[(long)e3 * D + lane];
                acc += (v0 + v1) + (v2 + v3);
            }
            for (; t < m; ++t) acc += edges[(long)sids[w][t] * D + lane];
        }
        acc2[dir] = acc;
    }

    float nf = nodes[(long)node * D + lane];
    sfeat[w][lane]       = nf;
    sfeat[w][64 + lane]  = acc2[0];
    sfeat[w][128 + lane] = acc2[1];

    float h = 0.f;
    if (lane < HID) {
        float h0 = 0.f, h1 = 0.f, h2 = 0.f, h3 = 0.f;
        for (int k = 0; k < IN_DIM; k += 4) {
            h0 += sfeat[w][k]     * W1[(k)     * HID + lane];
            h1 += sfeat[w][k + 1] * W1[(k + 1) * HID + lane];
            h2 += sfeat[w][k + 2] * W1[(k + 2) * HID + lane];
            h3 += sfeat[w][k + 3] * W1[(k + 3) * HID + lane];
        }
        h = fmaxf(b1[lane] + ((h0 + h1) + (h2 + h3)), 0.f);
    }
    float p0 = (lane < HID) ? h * W2[lane * 2 + 0] : 0.f;
    float p1 = (lane < HID) ? h * W2[lane * 2 + 1] : 0.f;
#pragma unroll
    for (int off = 32; off; off >>= 1) {
        p0 += __shfl_down(p0, off, 64);
        p1 += __shfl_down(p1, off, 64);
    }
    if (lane == 0)
        reinterpret_cast<float2*>(out)[node] = make_float2(p0 + b2[0], p1 + b2[1]);
}

// ---------------------------------------------------------------------------
// per-node MLP (fallback path only)
// ---------------------------------------------------------------------------
__global__ __launch_bounds__(256) void mlp_kernel(
    const float* __restrict__ nodes,
    const float* __restrict__ sent,
    const float* __restrict__ recv,
    const float* __restrict__ W1,
    const float* __restrict__ b1,
    const float* __restrict__ W2,
    const float* __restrict__ b2,
    float* __restrict__ out,
    int n)
{
    __shared__ float sW1[IN_DIM * HID];
    __shared__ float sb1[HID];
    __shared__ float sW2[HID * 2];
    __shared__ float sb2[2];

    for (int t = threadIdx.x; t < IN_DIM * HID; t += blockDim.x) sW1[t] = W1[t];
    if (threadIdx.x < HID)     sb1[threadIdx.x] = b1[threadIdx.x];
    if (threadIdx.x < HID * 2) sW2[threadIdx.x] = W2[threadIdx.x];
    if (threadIdx.x < 2)       sb2[threadIdx.x] = b2[threadIdx.x];
    __syncthreads();

    int node = blockIdx.x * blockDim.x + threadIdx.x;
    if (node >= n) return;

    float acc[HID];
#pragma unroll
    for (int j = 0; j < HID; ++j) acc[j] = sb1[j];

#pragma unroll
    for (int part = 0; part < 3; ++part) {
        const float* f = (part == 0 ? nodes : (part == 1 ? sent : recv)) + (long)node * D;
        const float* wgt = sW1 + part * D * HID;
        for (int k = 0; k < D; k += 4) {
            float4 fv = *reinterpret_cast<const float4*>(f + k);
#pragma unroll
            for (int j = 0; j < HID; ++j) {
                acc[j] += fv.x * wgt[(k + 0) * HID + j];
                acc[j] += fv.y * wgt[(k + 1) * HID + j];
                acc[j] += fv.z * wgt[(k + 2) * HID + j];
                acc[j] += fv.w * wgt[(k + 3) * HID + j];
            }
        }
    }

    float o0 = sb2[0], o1 = sb2[1];
#pragma unroll
    for (int j = 0; j < HID; ++j) {
        float h = fmaxf(acc[j], 0.f);
        o0 += h * sW2[j * 2 + 0];
        o1 += h * sW2[j * 2 + 1];
    }
    reinterpret_cast<float2*>(out)[node] = make_float2(o0, o1);
}

// ---------------------------------------------------------------------------
extern "C" void kernel_launch(void* const* d_in, const int* in_sizes, int n_in,
                              void* d_out, int out_size, void* d_ws, size_t ws_size,
                              hipStream_t stream) {
    const float* nodes     = (const float*)d_in[0];
    const float* edges     = (const float*)d_in[1];
    const int*   senders   = (const int*)d_in[2];
    const int*   receivers = (const int*)d_in[3];
    const float* W1        = (const float*)d_in[4];
    const float* b1        = (const float*)d_in[5];
    const float* W2        = (const float*)d_in[6];
    const float* b2        = (const float*)d_in[7];
    float* out = (float*)d_out;

    const int  n_nodes = in_sizes[0] / D;      // 100,000
    const long E       = in_sizes[2];          // 3,200,000
    const long total_items = 2 * E;            // 6.4M endpoint records

    const int NB      = (n_nodes + NPB - 1) / NPB;                 // 391
    const int nblocks = (int)((total_items + CHUNK - 1) / CHUNK);  // 782
    const int S       = (nblocks + SLICE - 1) / SLICE;             // 13

    const size_t sz_sent = (size_t)n_nodes * D * sizeof(float);    // 25.6 MB
    const size_t sz_pool = (size_t)total_items * sizeof(unsigned); // 25.6 MB
    const size_t sz_seg  = (size_t)n_nodes * sizeof(int4);         // 1.6 MB
    const size_t sz_nb   = (size_t)NBMAX * sizeof(int);
    const size_t sz_psum = (size_t)S * NB * sizeof(int);
    const size_t need    = 2 * sz_sent + 2 * sz_pool + sz_seg + 2 * sz_nb + sz_psum;
    const size_t sz_counts = (size_t)nblocks * NB * sizeof(int);   // ~1.2 MB

    char* wp = (char*)d_ws;
    float*    sent  = (float*)wp;           wp += sz_sent;
    float*    recv  = (float*)wp;           wp += sz_sent;
    unsigned* pool  = (unsigned*)wp;        wp += sz_pool;
    unsigned* pool2 = (unsigned*)wp;        wp += sz_pool;
    int4*     seg   = (int4*)wp;            wp += sz_seg;
    int*      tot   = (int*)wp;             wp += sz_nb;
    int*      base  = (int*)wp;             wp += sz_nb;
    int*      psum  = (int*)wp;
    int*      counts = (int*)sent;          // aliased; dead after scatter_ids

    if (ws_size < need || NB > NBMAX || sz_counts > sz_sent || E >= (1L << 23)) {
        long n4 = (long)n_nodes * D * 2 / 4;
        zero_ws_kernel<<<2048, 256, 0, stream>>>((float4*)d_ws, n4);
        long total = E * D;
        scatter_kernel<<<(int)((total + 255) / 256), 256, 0, stream>>>(
            edges, senders, receivers, sent, recv, total);
        mlp_kernel<<<(n_nodes + 255) / 256, 256, 0, stream>>>(
            nodes, sent, recv, W1, b1, W2, b2, out, n_nodes);
        return;
    }

    count_kernel<<<nblocks, 256, 0, stream>>>(senders, receivers, counts,
                                              NB, E, total_items);
    {
        dim3 g1((NB + 255) / 256, S);
        colscan1_kernel<<<g1, 256, 0, stream>>>(counts, psum, NB, nblocks);
        colfinish_kernel<<<1, 512, 0, stream>>>(psum, tot, base, NB, S);
    }
    scatter_ids_kernel<<<nblocks, 256, 0, stream>>>(senders, receivers, counts,
                                                    psum, base, pool, NB, E, total_items);
    sort_bucket_kernel<<<NB, 256, 0, stream>>>(pool, base, tot, pool2, seg, n_nodes);
    gmlp_kernel<<<(n_nodes + 3) / 4, 256, 0, stream>>>(edges, pool2, seg, nodes,
                                                       W1, b1, W2, b2, out, n_nodes);
}